// Round 16
// baseline (252.458 us; speedup 1.0000x reference)
//
#include <hip/hip_runtime.h>
#include <hip/hip_bf16.h>

#define B_ 8
#define L_ 256
#define T_ 2048
#define LM_ 4096
#define DFF_ 1024
#define D_ 84
#define H_ 4
#define HD_ 21
#define BL_ (B_*L_)          // 2048
#define VISF_ (L_*D_)        // 21504
#define VKS 56
#define VCHUNK (VISF_/VKS)   // 384
#define AKS 8
#define AKEYS (L_/AKS)       // 32

typedef __attribute__((ext_vector_type(8))) short bf16x8;
typedef __attribute__((ext_vector_type(4))) float f32x4;

struct bh4 { __hip_bfloat16 x, y, z, w; };

// packed fragment layout: X[R][K] -> Xp[R/16][K/8][16][8]
// elem (r,k) at ((r>>4)*(K/8) + (k>>3))*128 + (r&15)*8 + (k&7)

// ---------------- fused packing / conversion / build_src ----------------
__device__ __forceinline__ void dev_wT_pack(const float* __restrict__ W,
        __hip_bfloat16* __restrict__ Wp, int K, int N, int kb, int nb, int tid,
        float (*t)[33])
{
    int tx = tid & 31, ty = tid >> 5;
    #pragma unroll
    for (int i = 0; i < 4; ++i)
        t[ty + i*8][tx] = W[(size_t)(kb + ty + i*8)*N + nb + tx];
    __syncthreads();
    int KG = K >> 3;
    #pragma unroll
    for (int i = 0; i < 4; ++i) {
        int n = nb + ty + i*8, k = kb + tx;
        Wp[((size_t)(n>>4)*KG + (k>>3))*128 + (n&15)*8 + (k&7)] = __float2bfloat16(t[tx][ty + i*8]);
    }
}

__device__ __forceinline__ void dev_wTp_pack(const float* __restrict__ W,
        __hip_bfloat16* __restrict__ Wp, int K, int N, int KP, int kb, int nb, int tid,
        float (*t)[33])
{
    int tx = tid & 31, ty = tid >> 5;
    #pragma unroll
    for (int i = 0; i < 4; ++i) {
        int k = kb + ty + i*8, n = nb + tx;
        t[ty + i*8][tx] = (k < K && n < N) ? W[(size_t)k*N + n] : 0.0f;
    }
    __syncthreads();
    int KG = KP >> 3;
    #pragma unroll
    for (int i = 0; i < 4; ++i) {
        int n = nb + ty + i*8, k = kb + tx;
        Wp[((size_t)(n>>4)*KG + (k>>3))*128 + (n&15)*8 + (k&7)] = __float2bfloat16(t[tx][ty + i*8]);
    }
}

__device__ __forceinline__ void dev_f2b_pack(const float* __restrict__ in,
        __hip_bfloat16* __restrict__ out, int i)
{
    int row = i >> 9, kc = i & 511;
    const float4* p = reinterpret_cast<const float4*>(in + (size_t)row*4096 + kc*8);
    float4 v0 = p[0], v1 = p[1];
    bh4 a = { __float2bfloat16(v0.x), __float2bfloat16(v0.y),
              __float2bfloat16(v0.z), __float2bfloat16(v0.w) };
    bh4 b = { __float2bfloat16(v1.x), __float2bfloat16(v1.y),
              __float2bfloat16(v1.z), __float2bfloat16(v1.w) };
    __hip_bfloat16* o = out + ((size_t)(row>>4)*512 + kc)*128 + (row&15)*8;
    reinterpret_cast<bh4*>(o)[0] = a;
    reinterpret_cast<bh4*>(o)[1] = b;
}

__device__ __forceinline__ void dev_build_src(const float* __restrict__ vf,
        const float* __restrict__ gB, const float* __restrict__ cemb,
        float* __restrict__ src, float* __restrict__ neg, int row)
{
    float v[7];
    bool allz = true;
    #pragma unroll
    for (int c = 0; c < 7; ++c) { v[c] = vf[row*7 + c]; allz = allz && (v[c] == 0.0f); }
    neg[row] = allz ? -1e9f : 0.0f;
    float* s = src + (size_t)row * D_;
    const float TWO_PI = 6.28318530717958647692f;
    #pragma unroll
    for (int d = 0; d < 5; ++d) {
        float pmin = TWO_PI * (v[0]*gB[d] + v[1]*gB[5+d] + v[2]*gB[10+d]);
        float pmax = TWO_PI * (v[3]*gB[d] + v[4]*gB[5+d] + v[5]*gB[10+d]);
        s[d]      = sinf(pmin);  s[5+d]  = cosf(pmin);
        s[10+d]   = sinf(pmax);  s[15+d] = cosf(pmax);
    }
    int cls = (int)v[6];
    const float4* ce = reinterpret_cast<const float4*>(cemb + (size_t)cls*64);
    float4* so = reinterpret_cast<float4*>(s + 20);
    #pragma unroll
    for (int i = 0; i < 16; ++i) so[i] = ce[i];
}

// block ranges:
// [0,4096) w0_top  [4096,5120) w1  [5120,6144) w2  [6144,7168) w3
// [7168,7424) ff1 packs  [7424,7616) ff2 packs (packed [6][128][16][8])
// [7616,11712) grd pack  [11712,11720) build_src
__global__ __launch_bounds__(256) void k_pack_all(
        const float* __restrict__ grd, const float* __restrict__ w0,
        const float* __restrict__ w1, const float* __restrict__ w2,
        const float* __restrict__ w3, const float* __restrict__ w_ff1,
        const float* __restrict__ w_ff2,
        const float* __restrict__ vf, const float* __restrict__ gB,
        const float* __restrict__ cemb,
        __hip_bfloat16* __restrict__ grdb, __hip_bfloat16* __restrict__ w0t,
        __hip_bfloat16* __restrict__ w1t, __hip_bfloat16* __restrict__ w2t,
        __hip_bfloat16* __restrict__ w3t, __hip_bfloat16* __restrict__ wff1t,
        __hip_bfloat16* __restrict__ wff2t,
        float* __restrict__ src, float* __restrict__ neg)
{
    __shared__ float t[32][33];
    int blk = blockIdx.x, tid = threadIdx.x;
    if (blk < 4096) {
        dev_wT_pack(w0 + (size_t)VISF_*DFF_, w0t, LM_, DFF_,
                    (blk & 127)*32, (blk >> 7)*32, tid, t);
    } else if (blk < 5120) {
        int u = blk - 4096;
        dev_wT_pack(w1, w1t, DFF_, DFF_, (u & 31)*32, (u >> 5)*32, tid, t);
    } else if (blk < 6144) {
        int u = blk - 5120;
        dev_wT_pack(w2, w2t, DFF_, DFF_, (u & 31)*32, (u >> 5)*32, tid, t);
    } else if (blk < 7168) {
        int u = blk - 6144;
        dev_wT_pack(w3, w3t, DFF_, DFF_, (u & 31)*32, (u >> 5)*32, tid, t);
    } else if (blk < 7424) {
        int u = blk - 7168;
        int l = u >> 7; u &= 127;
        dev_wTp_pack(w_ff1 + (size_t)l*D_*DFF_, wff1t + (size_t)l*1024*128,
                     D_, DFF_, 128, (u & 3)*32, (u >> 2)*32, tid, t);
    } else if (blk < 7616) {
        int u = blk - 7424;
        int l = u / 96; u -= l*96;
        dev_wTp_pack(w_ff2 + (size_t)l*DFF_*D_, wff2t + (size_t)l*98304,
                     DFF_, D_, DFF_, (u % 32)*32, (u / 32)*32, tid, t);
    } else if (blk < 11712) {
        dev_f2b_pack(grd, grdb, (blk - 7616)*256 + tid);
    } else {
        dev_build_src(vf, gB, cemb, src, neg, (blk - 11712)*256 + tid);
    }
}

// ---------------- Stage B: encoder ----------------
__global__ __launch_bounds__(256) void k_qkv8(const float* __restrict__ src,
        const float* __restrict__ w_in, const float* __restrict__ b_in,
        float* __restrict__ qkv, int lay)
{
    __shared__ float s8[8][D_];
    int r0 = blockIdx.x * 8, tid = threadIdx.x;
    for (int idx = tid; idx < 8*D_; idx += 256) {
        int r = idx / D_, d = idx - r*D_;
        s8[r][d] = src[(size_t)(r0+r)*D_ + d];
    }
    __syncthreads();
    if (tid < 3*D_) {
        const float* w = w_in + (size_t)lay*D_*3*D_ + tid;
        float acc[8] = {};
        for (int d = 0; d < D_; ++d) {
            float wv = w[(size_t)d*3*D_];
            #pragma unroll
            for (int r = 0; r < 8; ++r) acc[r] = fmaf(s8[r][d], wv, acc[r]);
        }
        float bv = b_in[lay*3*D_ + tid];
        #pragma unroll
        for (int r = 0; r < 8; ++r) qkv[(size_t)(r0+r)*(3*D_) + tid] = acc[r] + bv;
    }
}

// split-K attention partials: grid (B*H, AKS), one thread per query
__global__ __launch_bounds__(256) void k_attn_part(const float* __restrict__ qkv,
        const float* __restrict__ neg, float* __restrict__ part)
{
    __shared__ float ks_[AKEYS*HD_], vs_[AKEYS*HD_], ns[AKEYS];
    int bh = blockIdx.x;
    int b = bh >> 2, h = bh & 3;
    int sp = blockIdx.y;
    int tid = threadIdx.x;
    int k0 = sp * AKEYS;
    for (int idx = tid; idx < AKEYS*HD_; idx += 256) {
        int l = idx / HD_, d = idx - l*HD_;
        size_t base = ((size_t)(b*L_ + k0 + l))*(3*D_) + h*HD_ + d;
        ks_[idx] = qkv[base + D_];
        vs_[idx] = qkv[base + 2*D_];
    }
    if (tid < AKEYS) ns[tid] = neg[b*L_ + k0 + tid];
    __syncthreads();
    float q[HD_];
    {
        size_t base = ((size_t)(b*L_ + tid))*(3*D_) + h*HD_;
        #pragma unroll
        for (int d = 0; d < HD_; ++d) q[d] = qkv[base + d];
    }
    const float scale = 0.21821789023599239f;  // 1/sqrt(21)
    float m_run = -INFINITY, l_run = 0.0f;
    float o[HD_];
    #pragma unroll
    for (int d = 0; d < HD_; ++d) o[d] = 0.0f;
    for (int m = 0; m < AKEYS; ++m) {
        const float* krow = &ks_[m*HD_];
        float sdot = 0.0f;
        #pragma unroll
        for (int d = 0; d < HD_; ++d) sdot = fmaf(q[d], krow[d], sdot);
        float sc = sdot * scale + ns[m];
        float nm = fmaxf(m_run, sc);
        float c = __expf(m_run - nm);
        float p = __expf(sc - nm);
        l_run = l_run * c + p;
        const float* vrow = &vs_[m*HD_];
        #pragma unroll
        for (int d = 0; d < HD_; ++d) o[d] = fmaf(p, vrow[d], o[d]*c);
        m_run = nm;
    }
    float* po = part + (((size_t)bh*AKS + sp)*L_ + tid)*24;
    #pragma unroll
    for (int d = 0; d < HD_; ++d) po[d] = o[d];
    po[21] = m_run;
    po[22] = l_run;
}

// fused: attn split-merge + out-proj + residual + LN; fp32 src + PACKED bf16 srcb
__global__ __launch_bounds__(128) void k_oproj_ln(const float* __restrict__ part,
        const float* __restrict__ w_out, const float* __restrict__ b_out,
        const float* __restrict__ ln_s, const float* __restrict__ ln_b,
        float* __restrict__ src, __hip_bfloat16* __restrict__ srcb, int lay)
{
    __shared__ float os[D_];
    __shared__ float r1[128], r2[128];
    int row = blockIdx.x, tid = threadIdx.x;
    int b = row >> 8, q = row & 255;
    if (tid < D_) {
        int h = tid / 21, d = tid - h*21;
        const float* pb = part + (((size_t)(b*H_ + h)*AKS)*L_ + q)*24;
        float m_tot = -INFINITY;
        #pragma unroll
        for (int sp = 0; sp < AKS; ++sp)
            m_tot = fmaxf(m_tot, pb[(size_t)sp*L_*24 + 21]);
        float l_tot = 0.0f, ov = 0.0f;
        #pragma unroll
        for (int sp = 0; sp < AKS; ++sp) {
            const float* pp = pb + (size_t)sp*L_*24;
            float e = __expf(pp[21] - m_tot);
            l_tot = fmaf(pp[22], e, l_tot);
            ov = fmaf(pp[d], e, ov);
        }
        os[tid] = ov / l_tot;
    }
    __syncthreads();
    float y = 0.0f;
    if (tid < D_) {
        const float* w = w_out + (size_t)lay*D_*D_ + tid;
        float acc = b_out[lay*D_ + tid];
        for (int d = 0; d < D_; ++d) acc = fmaf(os[d], w[(size_t)d*D_], acc);
        y = src[(size_t)row*D_ + tid] + acc;
    }
    r1[tid] = (tid < D_) ? y : 0.0f;
    r2[tid] = (tid < D_) ? y*y : 0.0f;
    __syncthreads();
    for (int s = 64; s > 0; s >>= 1) {
        if (tid < s) { r1[tid] += r1[tid+s]; r2[tid] += r2[tid+s]; }
        __syncthreads();
    }
    float mean = r1[0] * (1.0f/D_);
    float var  = r2[0] * (1.0f/D_) - mean*mean;
    float rstd = rsqrtf(var + 1e-5f);
    float out = 0.0f;
    if (tid < D_) {
        out = (y - mean)*rstd*ln_s[lay*D_+tid] + ln_b[lay*D_+tid];
        src[(size_t)row*D_ + tid] = out;
    }
    __hip_bfloat16 val = (tid < D_) ? __float2bfloat16(out) : __float2bfloat16(0.0f);
    srcb[((size_t)(row>>4)*16 + (tid>>3))*128 + (row&15)*8 + (tid&7)] = val;
}

// ---------------- fused FF2 (full-K direct-global MFMA) + bias + residual + LN ----
// grid 128 blocks x 128 thr; block = 16 rows. 2 waves over 48-col halves.
// NOTE: one mfma_16x16x32 consumes 4 k-groups (lane*8 spans 4 inner blocks) -> kg += 4.
__global__ __launch_bounds__(128) void k_ff2_ln(
        const __hip_bfloat16* __restrict__ hb,   // packed [128][128][16][8]
        const __hip_bfloat16* __restrict__ wp,   // packed [6][128][16][8]
        const float* __restrict__ b_ff2, const float* __restrict__ ln_s,
        const float* __restrict__ ln_b, float* __restrict__ src, int lay)
{
    __shared__ float yb[16][96];    // 6 KB
    int tid = threadIdx.x, wc = tid >> 6, lane = tid & 63;
    int l15 = lane & 15, l4 = lane >> 4;
    int mg = blockIdx.x;            // row-group 0..127, rows mg*16..+16
    const __hip_bfloat16* Aw = hb + ((size_t)mg * 128) * 128 + lane*8;
    const __hip_bfloat16* Bw = wp + ((size_t)(wc*3) * 128) * 128 + lane*8;
    f32x4 acc[3] = {};
    #pragma unroll 8
    for (int kg = 0; kg < 128; kg += 4) {
        bf16x8 a = *reinterpret_cast<const bf16x8*>(Aw + (size_t)kg*128);
        #pragma unroll
        for (int ni = 0; ni < 3; ++ni) {
            bf16x8 b = *reinterpret_cast<const bf16x8*>(Bw + ((size_t)ni*128 + kg)*128);
            acc[ni] = __builtin_amdgcn_mfma_f32_16x16x32_bf16(a, b, acc[ni], 0, 0, 0);
        }
    }
    #pragma unroll
    for (int ni = 0; ni < 3; ++ni)
        #pragma unroll
        for (int reg = 0; reg < 4; ++reg)
            yb[l4*4 + reg][wc*48 + ni*16 + l15] = acc[ni][reg];
    __syncthreads();
    // LN: 16 rows x 8 threads each
    int r = tid >> 3, c8 = tid & 7;
    int row = mg*16 + r;
    float s1 = 0.0f, s2 = 0.0f;
    for (int c = c8; c < D_; c += 8) {
        float y = yb[r][c] + b_ff2[lay*D_ + c] + src[(size_t)row*D_ + c];
        yb[r][c] = y;
        s1 += y; s2 += y*y;
    }
    #pragma unroll
    for (int m = 1; m < 8; m <<= 1) {
        s1 += __shfl_xor(s1, m);
        s2 += __shfl_xor(s2, m);
    }
    float mean = s1 * (1.0f/D_);
    float var  = s2 * (1.0f/D_) - mean*mean;
    float rstd = rsqrtf(var + 1e-5f);
    for (int c = c8; c < D_; c += 8)
        src[(size_t)row*D_ + c] = (yb[r][c] - mean)*rstd*ln_s[lay*D_ + c] + ln_b[lay*D_ + c];
}

// ---------------- vis part (fp32, exact, BW-optimized) ----------------
__global__ __launch_bounds__(256) void k_vis_gemm(const float* __restrict__ src,
        const float* __restrict__ w0, float* __restrict__ partials)
{
    __shared__ float vf[8][VCHUNK];        // 12 KB
    __shared__ float red[8][256][4];       // 32 KB
    int nt = blockIdx.x, sp = blockIdx.y, tid = threadIdx.x;
    int k0 = sp * VCHUNK;
    #pragma unroll
    for (int r = 0; r < 8; ++r)
        for (int c = tid; c < VCHUNK; c += 256)
            vf[r][c] = src[(size_t)r*VISF_ + k0 + c];
    __syncthreads();
    int ng = tid & 31;
    int kh = tid >> 5;          // 0..7, 48 k's each
    const float* wp = w0 + (size_t)(k0 + kh*(VCHUNK/8))*DFF_ + nt*128 + ng*4;
    float acc[8][4] = {};
    #pragma unroll 4
    for (int kk = 0; kk < VCHUNK/8; ++kk) {
        float4 w = *reinterpret_cast<const float4*>(wp + (size_t)kk*DFF_);
        #pragma unroll
        for (int m = 0; m < 8; ++m) {
            float sv = vf[m][kh*(VCHUNK/8) + kk];
            acc[m][0] = fmaf(sv, w.x, acc[m][0]);
            acc[m][1] = fmaf(sv, w.y, acc[m][1]);
            acc[m][2] = fmaf(sv, w.z, acc[m][2]);
            acc[m][3] = fmaf(sv, w.w, acc[m][3]);
        }
    }
    #pragma unroll
    for (int m = 0; m < 8; ++m)
        *reinterpret_cast<float4*>(&red[m][tid][0]) =
            make_float4(acc[m][0], acc[m][1], acc[m][2], acc[m][3]);
    __syncthreads();
    int m2 = tid >> 5, ng2 = tid & 31;
    float4 s = *reinterpret_cast<const float4*>(&red[m2][ng2][0]);
    #pragma unroll
    for (int j = 1; j < 8; ++j) {
        float4 v = *reinterpret_cast<const float4*>(&red[m2][j*32 + ng2][0]);
        s.x += v.x; s.y += v.y; s.z += v.z; s.w += v.w;
    }
    *reinterpret_cast<float4*>(
        &partials[(size_t)sp*8192 + m2*1024 + nt*128 + ng2*4]) = s;
}

__global__ __launch_bounds__(256) void k_vis_red(const float* __restrict__ partials,
        float* __restrict__ vis)
{
    int o = blockIdx.x*256 + threadIdx.x;
    float s = 0.0f;
    for (int sp = 0; sp < VKS; ++sp) s += partials[(size_t)sp*8192 + o];
    vis[o] = s;
}

// ---------------- direct-global MFMA GEMM (no LDS in main loop, no barriers) ----
template<bool ADD_VIS, int K>
__global__ __launch_bounds__(256) void mfma_gemm(
        const __hip_bfloat16* __restrict__ Ap,   // [M/16][K/8][16][8]
        const __hip_bfloat16* __restrict__ Bp,   // [1024/16][K/8][16][8]
        const float* __restrict__ bias,          // [1024]
        const float* __restrict__ vis,           // [8][1024]
        const int* __restrict__ bidx,            // [M]
        __hip_bfloat16* __restrict__ Cp)         // packed [M/16][128][16][8]
{
    constexpr int KG = K >> 3;
    constexpr int NG = 128;     // 1024/8
    __shared__ __align__(16) __hip_bfloat16 cst[64*128];   // 16 KB C-staging
    int tid = threadIdx.x, wave = tid >> 6, lane = tid & 63;
    int wr = wave >> 1, wc = wave & 1;
    int l15 = lane & 15, l4 = lane >> 4;
    int bm = blockIdx.x * 64, bn = blockIdx.y * 128;
    const __hip_bfloat16* Aw = Ap + ((size_t)((bm >> 4) + wr*2) * KG) * 128 + lane*8;
    const __hip_bfloat16* Bw = Bp + ((size_t)((bn >> 4) + wc*4) * KG) * 128 + lane*8;
    f32x4 acc[2][4] = {};

    #pragma unroll 4
    for (int kg = 0; kg < KG; kg += 4) {
        bf16x8 a[2], b[4];
        #pragma unroll
        for (int mi = 0; mi < 2; ++mi)
            a[mi] = *reinterpret_cast<const bf16x8*>(Aw + ((size_t)mi*KG + kg)*128);
        #pragma unroll
        for (int ni = 0; ni < 4; ++ni)
            b[ni] = *reinterpret_cast<const bf16x8*>(Bw + ((size_t)ni*KG + kg)*128);
        #pragma unroll
        for (int mi = 0; mi < 2; ++mi)
            #pragma unroll
            for (int ni = 0; ni < 4; ++ni)
                acc[mi][ni] = __builtin_amdgcn_mfma_f32_16x16x32_bf16(
                    a[mi], b[ni], acc[mi][ni], 0, 0, 0);
    }

    #pragma unroll
    for (int mi = 0; mi < 2; ++mi) {
        int mg = wr*2 + mi;
        #pragma unroll
        for (int ni = 0; ni < 4; ++ni) {
            int cg = wc*8 + ni*2 + (l15 >> 3);
            int c  = l15 & 7;
            int col = bn + cg*8 + c;
            float bv = bias[col];
            #pragma unroll
            for (int reg = 0; reg < 4; ++reg) {
                int r = l4*4 + reg;
                float v = acc[mi][ni][reg] + bv;
                if (ADD_VIS) v += vis[(size_t)bidx[bm + mg*16 + r]*1024 + col];
                v = fmaxf(v, 0.0f);
                cst[((mg*16 + cg)*16 + r)*8 + c] = __float2bfloat16(v);
            }
        }
    }
    __syncthreads();
    #pragma unroll
    for (int ch = tid; ch < 1024; ch += 256) {
        int mgcg = ch >> 4, r = ch & 15;
        int mg = mgcg >> 4, cg = mgcg & 15;
        size_t go = ((size_t)((bm >> 4) + mg) * NG + (bn >> 3) + cg) * 128 + r*8;
        *reinterpret_cast<bf16x8*>(Cp + go) =
            *reinterpret_cast<const bf16x8*>(cst + (size_t)ch*8);
    }
}

// final 1024 -> 6 (packed bf16 h)
__global__ __launch_bounds__(64) void k_final(const __hip_bfloat16* __restrict__ hp,
        const float* __restrict__ w4, const float* __restrict__ b4, float* __restrict__ out)
{
    int t = blockIdx.x, lane = threadIdx.x;
    int mg = t >> 4, r = t & 15;
    float acc[6] = {};
    #pragma unroll
    for (int it = 0; it < 2; ++it) {
        int kg = lane + it*64;
        bf16x8 h = *reinterpret_cast<const bf16x8*>(hp + ((size_t)mg*128 + kg)*128 + r*8);
        #pragma unroll
        for (int j = 0; j < 8; ++j) {
            unsigned short us = (unsigned short)h[j];
            float hv = __uint_as_float((unsigned)us << 16);
            int k = kg*8 + j;
            #pragma unroll
            for (int c = 0; c < 6; ++c) acc[c] = fmaf(hv, w4[k*6 + c], acc[c]);
        }
    }
    #pragma unroll
    for (int j = 0; j < 6; ++j)
        #pragma unroll
        for (int s = 32; s > 0; s >>= 1) acc[j] += __shfl_down(acc[j], s);
    if (lane == 0) {
        #pragma unroll
        for (int j = 0; j < 6; ++j) out[(size_t)t*6 + j] = acc[j] + b4[j];
    }
}

extern "C" void kernel_launch(void* const* d_in, const int* in_sizes, int n_in,
                              void* d_out, int out_size, void* d_ws, size_t ws_size,
                              hipStream_t stream)
{
    const float* grd   = (const float*)d_in[0];
    const float* vfeat = (const float*)d_in[1];
    const int*   tbi   = (const int*)  d_in[2];
    const float* gB    = (const float*)d_in[3];
    const float* cemb  = (const float*)d_in[4];
    const float* w_in  = (const float*)d_in[5];
    const float* b_in  = (const float*)d_in[6];
    const float* w_out = (const float*)d_in[7];
    const float* b_out = (const float*)d_in[8];
    const float* ln1_s = (const float*)d_in[9];
    const float* ln1_b = (const float*)d_in[10];
    const float* w_ff1 = (const float*)d_in[11];
    const float* b_ff1 = (const float*)d_in[12];
    const float* w_ff2 = (const float*)d_in[13];
    const float* b_ff2 = (const float*)d_in[14];
    const float* ln2_s = (const float*)d_in[15];
    const float* ln2_b = (const float*)d_in[16];
    const float* w0    = (const float*)d_in[17];
    const float* b0    = (const float*)d_in[18];
    const float* w1    = (const float*)d_in[19];
    const float* b1    = (const float*)d_in[20];
    const float* w2    = (const float*)d_in[21];
    const float* b2    = (const float*)d_in[22];
    const float* w3    = (const float*)d_in[23];
    const float* b3    = (const float*)d_in[24];
    const float* w4    = (const float*)d_in[25];
    const float* b4    = (const float*)d_in[26];

    float* ws = (float*)d_ws;
    float* src    = ws;                       // 172032
    float* neg    = src    + 172032;          // 2048
    float* qkv    = neg    + 2048;            // 516096
    float* vparts = qkv    + 516096;          // 458752 used
    float* visp   = vparts + 1376256;         // 8192
    float* ffpart = visp   + 8192;            // 1572864 (attn partials)
    float* fend   = ffpart + 1572864;
    __hip_bfloat16* grdb  = (__hip_bfloat16*)fend;       // 8388608 (packed)
    __hip_bfloat16* w0t   = grdb  + 8388608;             // 4194304 (packed)
    __hip_bfloat16* w1t   = w0t   + 4194304;             // 1048576 (packed)
    __hip_bfloat16* w2t   = w1t   + 1048576;             // 1048576 (packed)
    __hip_bfloat16* w3t   = w2t   + 1048576;             // 1048576 (packed)
    __hip_bfloat16* hab   = w3t   + 1048576;             // 2097152 (packed)
    __hip_bfloat16* hbb   = hab   + 2097152;             // 2097152 (packed)
    __hip_bfloat16* srcb  = hbb   + 2097152;             // 262144 (packed)
    __hip_bfloat16* wff1t = srcb  + 262144;              // 262144 (packed)
    __hip_bfloat16* wff2t = wff1t + 262144;              // 196608 (packed [6][128][16][8] x2)
    __hip_bfloat16* ffh   = hab;  // alias: hab unused until head GEMMs

    // single fused packing + build_src launch
    k_pack_all<<<11720, 256, 0, stream>>>(grd, w0, w1, w2, w3, w_ff1, w_ff2,
        vfeat, gB, cemb, grdb, w0t, w1t, w2t, w3t, wff1t, wff2t, src, neg);

    for (int lay = 0; lay < 2; ++lay) {
        k_qkv8     <<<BL_/8, 256, 0, stream>>>(src, w_in, b_in, qkv, lay);
        k_attn_part<<<dim3(B_*H_, AKS), 256, 0, stream>>>(qkv, neg, ffpart);
        k_oproj_ln <<<BL_, 128, 0, stream>>>(ffpart, w_out, b_out, ln1_s, ln1_b, src, srcb, lay);
        mfma_gemm<false, 128><<<dim3(32, 8), 256, 0, stream>>>(
            srcb, wff1t + (size_t)lay*1024*128, b_ff1 + lay*DFF_, nullptr, nullptr, ffh);
        k_ff2_ln<<<128, 128, 0, stream>>>(
            ffh, wff2t + (size_t)lay*98304, b_ff2, ln2_s, ln2_b, src, lay);
    }

    k_vis_gemm<<<dim3(8, VKS), 256, 0, stream>>>(src, w0, vparts);
    k_vis_red<<<32, 256, 0, stream>>>(vparts, visp);

    dim3 mg(T_/64, DFF_/128);   // (32, 8)
    mfma_gemm<true,  LM_ ><<<mg, 256, 0, stream>>>(grdb, w0t, b0, visp, tbi, hab);
    mfma_gemm<false, DFF_><<<mg, 256, 0, stream>>>(hab,  w1t, b1, nullptr, nullptr, hbb);
    mfma_gemm<false, DFF_><<<mg, 256, 0, stream>>>(hbb,  w2t, b2, nullptr, nullptr, hab);
    mfma_gemm<false, DFF_><<<mg, 256, 0, stream>>>(hab,  w3t, b3, nullptr, nullptr, hbb);

    k_final<<<T_, 64, 0, stream>>>(hbb, w4, b4, (float*)d_out);
}

// Round 17
// 240.444 us; speedup vs baseline: 1.0500x; 1.0500x over previous
//
#include <hip/hip_runtime.h>
#include <hip/hip_bf16.h>

#define B_ 8
#define L_ 256
#define T_ 2048
#define LM_ 4096
#define DFF_ 1024
#define D_ 84
#define H_ 4
#define HD_ 21
#define BL_ (B_*L_)          // 2048
#define VISF_ (L_*D_)        // 21504
#define VKS 56
#define VCHUNK (VISF_/VKS)   // 384
#define AKS 8
#define AKEYS (L_/AKS)       // 32

typedef __attribute__((ext_vector_type(8))) short bf16x8;
typedef __attribute__((ext_vector_type(4))) float f32x4;

struct bh4 { __hip_bfloat16 x, y, z, w; };

// packed fragment layout: X[R][K] -> Xp[R/16][K/8][16][8]
// elem (r,k) at ((r>>4)*(K/8) + (k>>3))*128 + (r&15)*8 + (k&7)

// ---------------- fused packing / conversion / build_src ----------------
__device__ __forceinline__ void dev_wT_pack(const float* __restrict__ W,
        __hip_bfloat16* __restrict__ Wp, int K, int N, int kb, int nb, int tid,
        float (*t)[33])
{
    int tx = tid & 31, ty = tid >> 5;
    #pragma unroll
    for (int i = 0; i < 4; ++i)
        t[ty + i*8][tx] = W[(size_t)(kb + ty + i*8)*N + nb + tx];
    __syncthreads();
    int KG = K >> 3;
    #pragma unroll
    for (int i = 0; i < 4; ++i) {
        int n = nb + ty + i*8, k = kb + tx;
        Wp[((size_t)(n>>4)*KG + (k>>3))*128 + (n&15)*8 + (k&7)] = __float2bfloat16(t[tx][ty + i*8]);
    }
}

__device__ __forceinline__ void dev_wTp_pack(const float* __restrict__ W,
        __hip_bfloat16* __restrict__ Wp, int K, int N, int KP, int kb, int nb, int tid,
        float (*t)[33])
{
    int tx = tid & 31, ty = tid >> 5;
    #pragma unroll
    for (int i = 0; i < 4; ++i) {
        int k = kb + ty + i*8, n = nb + tx;
        t[ty + i*8][tx] = (k < K && n < N) ? W[(size_t)k*N + n] : 0.0f;
    }
    __syncthreads();
    int KG = KP >> 3;
    #pragma unroll
    for (int i = 0; i < 4; ++i) {
        int n = nb + ty + i*8, k = kb + tx;
        Wp[((size_t)(n>>4)*KG + (k>>3))*128 + (n&15)*8 + (k&7)] = __float2bfloat16(t[tx][ty + i*8]);
    }
}

__device__ __forceinline__ void dev_f2b_pack(const float* __restrict__ in,
        __hip_bfloat16* __restrict__ out, int i)
{
    int row = i >> 9, kc = i & 511;
    const float4* p = reinterpret_cast<const float4*>(in + (size_t)row*4096 + kc*8);
    float4 v0 = p[0], v1 = p[1];
    bh4 a = { __float2bfloat16(v0.x), __float2bfloat16(v0.y),
              __float2bfloat16(v0.z), __float2bfloat16(v0.w) };
    bh4 b = { __float2bfloat16(v1.x), __float2bfloat16(v1.y),
              __float2bfloat16(v1.z), __float2bfloat16(v1.w) };
    __hip_bfloat16* o = out + ((size_t)(row>>4)*512 + kc)*128 + (row&15)*8;
    reinterpret_cast<bh4*>(o)[0] = a;
    reinterpret_cast<bh4*>(o)[1] = b;
}

__device__ __forceinline__ void dev_build_src(const float* __restrict__ vf,
        const float* __restrict__ gB, const float* __restrict__ cemb,
        float* __restrict__ src, float* __restrict__ neg, int row)
{
    float v[7];
    bool allz = true;
    #pragma unroll
    for (int c = 0; c < 7; ++c) { v[c] = vf[row*7 + c]; allz = allz && (v[c] == 0.0f); }
    neg[row] = allz ? -1e9f : 0.0f;
    float* s = src + (size_t)row * D_;
    const float TWO_PI = 6.28318530717958647692f;
    #pragma unroll
    for (int d = 0; d < 5; ++d) {
        float pmin = TWO_PI * (v[0]*gB[d] + v[1]*gB[5+d] + v[2]*gB[10+d]);
        float pmax = TWO_PI * (v[3]*gB[d] + v[4]*gB[5+d] + v[5]*gB[10+d]);
        s[d]      = sinf(pmin);  s[5+d]  = cosf(pmin);
        s[10+d]   = sinf(pmax);  s[15+d] = cosf(pmax);
    }
    int cls = (int)v[6];
    const float4* ce = reinterpret_cast<const float4*>(cemb + (size_t)cls*64);
    float4* so = reinterpret_cast<float4*>(s + 20);
    #pragma unroll
    for (int i = 0; i < 16; ++i) so[i] = ce[i];
}

// block ranges:
// [0,4096) w0_top  [4096,5120) w1  [5120,6144) w2  [6144,7168) w3
// [7168,7424) ff1 packs  [7424,7616) ff2 packs (packed [6][128][16][8])
// [7616,11712) grd pack  [11712,11720) build_src
__global__ __launch_bounds__(256) void k_pack_all(
        const float* __restrict__ grd, const float* __restrict__ w0,
        const float* __restrict__ w1, const float* __restrict__ w2,
        const float* __restrict__ w3, const float* __restrict__ w_ff1,
        const float* __restrict__ w_ff2,
        const float* __restrict__ vf, const float* __restrict__ gB,
        const float* __restrict__ cemb,
        __hip_bfloat16* __restrict__ grdb, __hip_bfloat16* __restrict__ w0t,
        __hip_bfloat16* __restrict__ w1t, __hip_bfloat16* __restrict__ w2t,
        __hip_bfloat16* __restrict__ w3t, __hip_bfloat16* __restrict__ wff1t,
        __hip_bfloat16* __restrict__ wff2t,
        float* __restrict__ src, float* __restrict__ neg)
{
    __shared__ float t[32][33];
    int blk = blockIdx.x, tid = threadIdx.x;
    if (blk < 4096) {
        dev_wT_pack(w0 + (size_t)VISF_*DFF_, w0t, LM_, DFF_,
                    (blk & 127)*32, (blk >> 7)*32, tid, t);
    } else if (blk < 5120) {
        int u = blk - 4096;
        dev_wT_pack(w1, w1t, DFF_, DFF_, (u & 31)*32, (u >> 5)*32, tid, t);
    } else if (blk < 6144) {
        int u = blk - 5120;
        dev_wT_pack(w2, w2t, DFF_, DFF_, (u & 31)*32, (u >> 5)*32, tid, t);
    } else if (blk < 7168) {
        int u = blk - 6144;
        dev_wT_pack(w3, w3t, DFF_, DFF_, (u & 31)*32, (u >> 5)*32, tid, t);
    } else if (blk < 7424) {
        int u = blk - 7168;
        int l = u >> 7; u &= 127;
        dev_wTp_pack(w_ff1 + (size_t)l*D_*DFF_, wff1t + (size_t)l*1024*128,
                     D_, DFF_, 128, (u & 3)*32, (u >> 2)*32, tid, t);
    } else if (blk < 7616) {
        int u = blk - 7424;
        int l = u / 96; u -= l*96;
        dev_wTp_pack(w_ff2 + (size_t)l*DFF_*D_, wff2t + (size_t)l*98304,
                     DFF_, D_, DFF_, (u % 32)*32, (u / 32)*32, tid, t);
    } else if (blk < 11712) {
        dev_f2b_pack(grd, grdb, (blk - 7616)*256 + tid);
    } else {
        dev_build_src(vf, gB, cemb, src, neg, (blk - 11712)*256 + tid);
    }
}

// ---------------- Stage B: encoder ----------------
__global__ __launch_bounds__(256) void k_qkv8(const float* __restrict__ src,
        const float* __restrict__ w_in, const float* __restrict__ b_in,
        float* __restrict__ qkv, int lay)
{
    __shared__ float s8[8][D_];
    int r0 = blockIdx.x * 8, tid = threadIdx.x;
    for (int idx = tid; idx < 8*D_; idx += 256) {
        int r = idx / D_, d = idx - r*D_;
        s8[r][d] = src[(size_t)(r0+r)*D_ + d];
    }
    __syncthreads();
    if (tid < 3*D_) {
        const float* w = w_in + (size_t)lay*D_*3*D_ + tid;
        float acc[8] = {};
        for (int d = 0; d < D_; ++d) {
            float wv = w[(size_t)d*3*D_];
            #pragma unroll
            for (int r = 0; r < 8; ++r) acc[r] = fmaf(s8[r][d], wv, acc[r]);
        }
        float bv = b_in[lay*3*D_ + tid];
        #pragma unroll
        for (int r = 0; r < 8; ++r) qkv[(size_t)(r0+r)*(3*D_) + tid] = acc[r] + bv;
    }
}

// split-K attention partials: grid (B*H, AKS), one thread per query
__global__ __launch_bounds__(256) void k_attn_part(const float* __restrict__ qkv,
        const float* __restrict__ neg, float* __restrict__ part)
{
    __shared__ float ks_[AKEYS*HD_], vs_[AKEYS*HD_], ns[AKEYS];
    int bh = blockIdx.x;
    int b = bh >> 2, h = bh & 3;
    int sp = blockIdx.y;
    int tid = threadIdx.x;
    int k0 = sp * AKEYS;
    for (int idx = tid; idx < AKEYS*HD_; idx += 256) {
        int l = idx / HD_, d = idx - l*HD_;
        size_t base = ((size_t)(b*L_ + k0 + l))*(3*D_) + h*HD_ + d;
        ks_[idx] = qkv[base + D_];
        vs_[idx] = qkv[base + 2*D_];
    }
    if (tid < AKEYS) ns[tid] = neg[b*L_ + k0 + tid];
    __syncthreads();
    float q[HD_];
    {
        size_t base = ((size_t)(b*L_ + tid))*(3*D_) + h*HD_;
        #pragma unroll
        for (int d = 0; d < HD_; ++d) q[d] = qkv[base + d];
    }
    const float scale = 0.21821789023599239f;  // 1/sqrt(21)
    float m_run = -INFINITY, l_run = 0.0f;
    float o[HD_];
    #pragma unroll
    for (int d = 0; d < HD_; ++d) o[d] = 0.0f;
    for (int m = 0; m < AKEYS; ++m) {
        const float* krow = &ks_[m*HD_];
        float sdot = 0.0f;
        #pragma unroll
        for (int d = 0; d < HD_; ++d) sdot = fmaf(q[d], krow[d], sdot);
        float sc = sdot * scale + ns[m];
        float nm = fmaxf(m_run, sc);
        float c = __expf(m_run - nm);
        float p = __expf(sc - nm);
        l_run = l_run * c + p;
        const float* vrow = &vs_[m*HD_];
        #pragma unroll
        for (int d = 0; d < HD_; ++d) o[d] = fmaf(p, vrow[d], o[d]*c);
        m_run = nm;
    }
    float* po = part + (((size_t)bh*AKS + sp)*L_ + tid)*24;
    #pragma unroll
    for (int d = 0; d < HD_; ++d) po[d] = o[d];
    po[21] = m_run;
    po[22] = l_run;
}

// fused: attn split-merge + out-proj + residual + LN; fp32 src + PACKED bf16 srcb
__global__ __launch_bounds__(128) void k_oproj_ln(const float* __restrict__ part,
        const float* __restrict__ w_out, const float* __restrict__ b_out,
        const float* __restrict__ ln_s, const float* __restrict__ ln_b,
        float* __restrict__ src, __hip_bfloat16* __restrict__ srcb, int lay)
{
    __shared__ float os[D_];
    __shared__ float r1[128], r2[128];
    int row = blockIdx.x, tid = threadIdx.x;
    int b = row >> 8, q = row & 255;
    if (tid < D_) {
        int h = tid / 21, d = tid - h*21;
        const float* pb = part + (((size_t)(b*H_ + h)*AKS)*L_ + q)*24;
        float m_tot = -INFINITY;
        #pragma unroll
        for (int sp = 0; sp < AKS; ++sp)
            m_tot = fmaxf(m_tot, pb[(size_t)sp*L_*24 + 21]);
        float l_tot = 0.0f, ov = 0.0f;
        #pragma unroll
        for (int sp = 0; sp < AKS; ++sp) {
            const float* pp = pb + (size_t)sp*L_*24;
            float e = __expf(pp[21] - m_tot);
            l_tot = fmaf(pp[22], e, l_tot);
            ov = fmaf(pp[d], e, ov);
        }
        os[tid] = ov / l_tot;
    }
    __syncthreads();
    float y = 0.0f;
    if (tid < D_) {
        const float* w = w_out + (size_t)lay*D_*D_ + tid;
        float acc = b_out[lay*D_ + tid];
        for (int d = 0; d < D_; ++d) acc = fmaf(os[d], w[(size_t)d*D_], acc);
        y = src[(size_t)row*D_ + tid] + acc;
    }
    r1[tid] = (tid < D_) ? y : 0.0f;
    r2[tid] = (tid < D_) ? y*y : 0.0f;
    __syncthreads();
    for (int s = 64; s > 0; s >>= 1) {
        if (tid < s) { r1[tid] += r1[tid+s]; r2[tid] += r2[tid+s]; }
        __syncthreads();
    }
    float mean = r1[0] * (1.0f/D_);
    float var  = r2[0] * (1.0f/D_) - mean*mean;
    float rstd = rsqrtf(var + 1e-5f);
    float out = 0.0f;
    if (tid < D_) {
        out = (y - mean)*rstd*ln_s[lay*D_+tid] + ln_b[lay*D_+tid];
        src[(size_t)row*D_ + tid] = out;
    }
    __hip_bfloat16 val = (tid < D_) ? __float2bfloat16(out) : __float2bfloat16(0.0f);
    srcb[((size_t)(row>>4)*16 + (tid>>3))*128 + (row&15)*8 + (tid&7)] = val;
}

// FF2 direct-global packed MFMA: part[sp][2048][96] over K-slice sp*128..+128
// grid (32, 8); 4 waves 2x2: wave-tile 32 rows x 48 cols. (round-14 proven)
__global__ __launch_bounds__(256) void k_ff2_mfma(
        const __hip_bfloat16* __restrict__ hb,   // packed [128][128][16][8]
        const __hip_bfloat16* __restrict__ wp,   // packed [6][128][16][8]
        float* __restrict__ part)                // [8][2048][96]
{
    int tid = threadIdx.x, wave = tid >> 6, lane = tid & 63;
    int wr = wave >> 1, wc = wave & 1;
    int l15 = lane & 15, l4 = lane >> 4;
    int bm = blockIdx.x * 64, sp = blockIdx.y;
    const __hip_bfloat16* Aw = hb + ((size_t)((bm >> 4) + wr*2) * 128) * 128 + lane*8;
    const __hip_bfloat16* Bw = wp + ((size_t)(wc*3) * 128) * 128 + lane*8;
    f32x4 acc[2][3] = {};
    int kg0 = sp * 16;
    #pragma unroll
    for (int kk = 0; kk < 16; kk += 4) {
        int kg = kg0 + kk;
        bf16x8 a[2], b[3];
        #pragma unroll
        for (int mi = 0; mi < 2; ++mi)
            a[mi] = *reinterpret_cast<const bf16x8*>(Aw + ((size_t)mi*128 + kg)*128);
        #pragma unroll
        for (int ni = 0; ni < 3; ++ni)
            b[ni] = *reinterpret_cast<const bf16x8*>(Bw + ((size_t)ni*128 + kg)*128);
        #pragma unroll
        for (int mi = 0; mi < 2; ++mi)
            #pragma unroll
            for (int ni = 0; ni < 3; ++ni)
                acc[mi][ni] = __builtin_amdgcn_mfma_f32_16x16x32_bf16(
                    a[mi], b[ni], acc[mi][ni], 0, 0, 0);
    }
    float* po = part + (size_t)sp*(2048*96);
    #pragma unroll
    for (int mi = 0; mi < 2; ++mi)
        #pragma unroll
        for (int reg = 0; reg < 4; ++reg) {
            int row = bm + wr*32 + mi*16 + l4*4 + reg;
            #pragma unroll
            for (int ni = 0; ni < 3; ++ni) {
                int col = wc*48 + ni*16 + l15;
                po[(size_t)row*96 + col] = acc[mi][ni][reg];
            }
        }
}

// reduce split-K partials + bias + residual + LN (over the true 84 cols)
__global__ __launch_bounds__(128) void k_ff2ln_red(const float* __restrict__ part,
        const float* __restrict__ b_ff2, const float* __restrict__ ln_s,
        const float* __restrict__ ln_b, float* __restrict__ src, int lay)
{
    __shared__ float r1[128], r2[128];
    int row = blockIdx.x, tid = threadIdx.x;
    float y = 0.0f;
    if (tid < D_) {
        #pragma unroll
        for (int sp = 0; sp < 8; ++sp)
            y += part[(size_t)sp*(2048*96) + (size_t)row*96 + tid];
        y += b_ff2[lay*D_ + tid] + src[(size_t)row*D_ + tid];
    }
    r1[tid] = (tid < D_) ? y : 0.0f;
    r2[tid] = (tid < D_) ? y*y : 0.0f;
    __syncthreads();
    for (int s = 64; s > 0; s >>= 1) {
        if (tid < s) { r1[tid] += r1[tid+s]; r2[tid] += r2[tid+s]; }
        __syncthreads();
    }
    float mean = r1[0] * (1.0f/D_);
    float var  = r2[0] * (1.0f/D_) - mean*mean;
    float rstd = rsqrtf(var + 1e-5f);
    if (tid < D_)
        src[(size_t)row*D_ + tid] = (y - mean)*rstd*ln_s[lay*D_+tid] + ln_b[lay*D_+tid];
}

// ---------------- vis part (fp32, exact, BW-optimized) ----------------
__global__ __launch_bounds__(256) void k_vis_gemm(const float* __restrict__ src,
        const float* __restrict__ w0, float* __restrict__ partials)
{
    __shared__ float vf[8][VCHUNK];        // 12 KB
    __shared__ float red[8][256][4];       // 32 KB
    int nt = blockIdx.x, sp = blockIdx.y, tid = threadIdx.x;
    int k0 = sp * VCHUNK;
    #pragma unroll
    for (int r = 0; r < 8; ++r)
        for (int c = tid; c < VCHUNK; c += 256)
            vf[r][c] = src[(size_t)r*VISF_ + k0 + c];
    __syncthreads();
    int ng = tid & 31;
    int kh = tid >> 5;          // 0..7, 48 k's each
    const float* wp = w0 + (size_t)(k0 + kh*(VCHUNK/8))*DFF_ + nt*128 + ng*4;
    float acc[8][4] = {};
    #pragma unroll 4
    for (int kk = 0; kk < VCHUNK/8; ++kk) {
        float4 w = *reinterpret_cast<const float4*>(wp + (size_t)kk*DFF_);
        #pragma unroll
        for (int m = 0; m < 8; ++m) {
            float sv = vf[m][kh*(VCHUNK/8) + kk];
            acc[m][0] = fmaf(sv, w.x, acc[m][0]);
            acc[m][1] = fmaf(sv, w.y, acc[m][1]);
            acc[m][2] = fmaf(sv, w.z, acc[m][2]);
            acc[m][3] = fmaf(sv, w.w, acc[m][3]);
        }
    }
    #pragma unroll
    for (int m = 0; m < 8; ++m)
        *reinterpret_cast<float4*>(&red[m][tid][0]) =
            make_float4(acc[m][0], acc[m][1], acc[m][2], acc[m][3]);
    __syncthreads();
    int m2 = tid >> 5, ng2 = tid & 31;
    float4 s = *reinterpret_cast<const float4*>(&red[m2][ng2][0]);
    #pragma unroll
    for (int j = 1; j < 8; ++j) {
        float4 v = *reinterpret_cast<const float4*>(&red[m2][j*32 + ng2][0]);
        s.x += v.x; s.y += v.y; s.z += v.z; s.w += v.w;
    }
    *reinterpret_cast<float4*>(
        &partials[(size_t)sp*8192 + m2*1024 + nt*128 + ng2*4]) = s;
}

__global__ __launch_bounds__(256) void k_vis_red(const float* __restrict__ partials,
        float* __restrict__ vis)
{
    int o = blockIdx.x*256 + threadIdx.x;
    float s = 0.0f;
    for (int sp = 0; sp < VKS; ++sp) s += partials[(size_t)sp*8192 + o];
    vis[o] = s;
}

// ---------------- direct-global MFMA GEMM (no LDS in main loop, no barriers) ----
template<bool ADD_VIS, int K>
__global__ __launch_bounds__(256) void mfma_gemm(
        const __hip_bfloat16* __restrict__ Ap,   // [M/16][K/8][16][8]
        const __hip_bfloat16* __restrict__ Bp,   // [1024/16][K/8][16][8]
        const float* __restrict__ bias,          // [1024]
        const float* __restrict__ vis,           // [8][1024]
        const int* __restrict__ bidx,            // [M]
        __hip_bfloat16* __restrict__ Cp)         // packed [M/16][128][16][8]
{
    constexpr int KG = K >> 3;
    constexpr int NG = 128;     // 1024/8
    __shared__ __align__(16) __hip_bfloat16 cst[64*128];   // 16 KB C-staging
    int tid = threadIdx.x, wave = tid >> 6, lane = tid & 63;
    int wr = wave >> 1, wc = wave & 1;
    int l15 = lane & 15, l4 = lane >> 4;
    int bm = blockIdx.x * 64, bn = blockIdx.y * 128;
    const __hip_bfloat16* Aw = Ap + ((size_t)((bm >> 4) + wr*2) * KG) * 128 + lane*8;
    const __hip_bfloat16* Bw = Bp + ((size_t)((bn >> 4) + wc*4) * KG) * 128 + lane*8;
    f32x4 acc[2][4] = {};

    #pragma unroll 4
    for (int kg = 0; kg < KG; kg += 4) {
        bf16x8 a[2], b[4];
        #pragma unroll
        for (int mi = 0; mi < 2; ++mi)
            a[mi] = *reinterpret_cast<const bf16x8*>(Aw + ((size_t)mi*KG + kg)*128);
        #pragma unroll
        for (int ni = 0; ni < 4; ++ni)
            b[ni] = *reinterpret_cast<const bf16x8*>(Bw + ((size_t)ni*KG + kg)*128);
        #pragma unroll
        for (int mi = 0; mi < 2; ++mi)
            #pragma unroll
            for (int ni = 0; ni < 4; ++ni)
                acc[mi][ni] = __builtin_amdgcn_mfma_f32_16x16x32_bf16(
                    a[mi], b[ni], acc[mi][ni], 0, 0, 0);
    }

    #pragma unroll
    for (int mi = 0; mi < 2; ++mi) {
        int mg = wr*2 + mi;
        #pragma unroll
        for (int ni = 0; ni < 4; ++ni) {
            int cg = wc*8 + ni*2 + (l15 >> 3);
            int c  = l15 & 7;
            int col = bn + cg*8 + c;
            float bv = bias[col];
            #pragma unroll
            for (int reg = 0; reg < 4; ++reg) {
                int r = l4*4 + reg;
                float v = acc[mi][ni][reg] + bv;
                if (ADD_VIS) v += vis[(size_t)bidx[bm + mg*16 + r]*1024 + col];
                v = fmaxf(v, 0.0f);
                cst[((mg*16 + cg)*16 + r)*8 + c] = __float2bfloat16(v);
            }
        }
    }
    __syncthreads();
    #pragma unroll
    for (int ch = tid; ch < 1024; ch += 256) {
        int mgcg = ch >> 4, r = ch & 15;
        int mg = mgcg >> 4, cg = mgcg & 15;
        size_t go = ((size_t)((bm >> 4) + mg) * NG + (bn >> 3) + cg) * 128 + r*8;
        *reinterpret_cast<bf16x8*>(Cp + go) =
            *reinterpret_cast<const bf16x8*>(cst + (size_t)ch*8);
    }
}

// final 1024 -> 6 (packed bf16 h)
__global__ __launch_bounds__(64) void k_final(const __hip_bfloat16* __restrict__ hp,
        const float* __restrict__ w4, const float* __restrict__ b4, float* __restrict__ out)
{
    int t = blockIdx.x, lane = threadIdx.x;
    int mg = t >> 4, r = t & 15;
    float acc[6] = {};
    #pragma unroll
    for (int it = 0; it < 2; ++it) {
        int kg = lane + it*64;
        bf16x8 h = *reinterpret_cast<const bf16x8*>(hp + ((size_t)mg*128 + kg)*128 + r*8);
        #pragma unroll
        for (int j = 0; j < 8; ++j) {
            unsigned short us = (unsigned short)h[j];
            float hv = __uint_as_float((unsigned)us << 16);
            int k = kg*8 + j;
            #pragma unroll
            for (int c = 0; c < 6; ++c) acc[c] = fmaf(hv, w4[k*6 + c], acc[c]);
        }
    }
    #pragma unroll
    for (int j = 0; j < 6; ++j)
        #pragma unroll
        for (int s = 32; s > 0; s >>= 1) acc[j] += __shfl_down(acc[j], s);
    if (lane == 0) {
        #pragma unroll
        for (int j = 0; j < 6; ++j) out[(size_t)t*6 + j] = acc[j] + b4[j];
    }
}

extern "C" void kernel_launch(void* const* d_in, const int* in_sizes, int n_in,
                              void* d_out, int out_size, void* d_ws, size_t ws_size,
                              hipStream_t stream)
{
    const float* grd   = (const float*)d_in[0];
    const float* vfeat = (const float*)d_in[1];
    const int*   tbi   = (const int*)  d_in[2];
    const float* gB    = (const float*)d_in[3];
    const float* cemb  = (const float*)d_in[4];
    const float* w_in  = (const float*)d_in[5];
    const float* b_in  = (const float*)d_in[6];
    const float* w_out = (const float*)d_in[7];
    const float* b_out = (const float*)d_in[8];
    const float* ln1_s = (const float*)d_in[9];
    const float* ln1_b = (const float*)d_in[10];
    const float* w_ff1 = (const float*)d_in[11];
    const float* b_ff1 = (const float*)d_in[12];
    const float* w_ff2 = (const float*)d_in[13];
    const float* b_ff2 = (const float*)d_in[14];
    const float* ln2_s = (const float*)d_in[15];
    const float* ln2_b = (const float*)d_in[16];
    const float* w0    = (const float*)d_in[17];
    const float* b0    = (const float*)d_in[18];
    const float* w1    = (const float*)d_in[19];
    const float* b1    = (const float*)d_in[20];
    const float* w2    = (const float*)d_in[21];
    const float* b2    = (const float*)d_in[22];
    const float* w3    = (const float*)d_in[23];
    const float* b3    = (const float*)d_in[24];
    const float* w4    = (const float*)d_in[25];
    const float* b4    = (const float*)d_in[26];

    float* ws = (float*)d_ws;
    float* src    = ws;                       // 172032
    float* neg    = src    + 172032;          // 2048
    float* qkv    = neg    + 2048;            // 516096
    float* vparts = qkv    + 516096;          // 458752 used
    float* visp   = vparts + 1376256;         // 8192
    float* ffpart = visp   + 8192;            // 1572864 (attn partials / ff2 partials)
    float* fend   = ffpart + 1572864;
    __hip_bfloat16* grdb  = (__hip_bfloat16*)fend;       // 8388608 (packed)
    __hip_bfloat16* w0t   = grdb  + 8388608;             // 4194304 (packed)
    __hip_bfloat16* w1t   = w0t   + 4194304;             // 1048576 (packed)
    __hip_bfloat16* w2t   = w1t   + 1048576;             // 1048576 (packed)
    __hip_bfloat16* w3t   = w2t   + 1048576;             // 1048576 (packed)
    __hip_bfloat16* hab   = w3t   + 1048576;             // 2097152 (packed)
    __hip_bfloat16* hbb   = hab   + 2097152;             // 2097152 (packed)
    __hip_bfloat16* srcb  = hbb   + 2097152;             // 262144 (packed)
    __hip_bfloat16* wff1t = srcb  + 262144;              // 262144 (packed)
    __hip_bfloat16* wff2t = wff1t + 262144;              // 196608 (packed [6][128][16][8] x2)
    __hip_bfloat16* ffh   = hab;  // alias: hab unused until head GEMMs

    // single fused packing + build_src launch
    k_pack_all<<<11720, 256, 0, stream>>>(grd, w0, w1, w2, w3, w_ff1, w_ff2,
        vfeat, gB, cemb, grdb, w0t, w1t, w2t, w3t, wff1t, wff2t, src, neg);

    for (int lay = 0; lay < 2; ++lay) {
        k_qkv8     <<<BL_/8, 256, 0, stream>>>(src, w_in, b_in, qkv, lay);
        k_attn_part<<<dim3(B_*H_, AKS), 256, 0, stream>>>(qkv, neg, ffpart);
        k_oproj_ln <<<BL_, 128, 0, stream>>>(ffpart, w_out, b_out, ln1_s, ln1_b, src, srcb, lay);
        mfma_gemm<false, 128><<<dim3(32, 8), 256, 0, stream>>>(
            srcb, wff1t + (size_t)lay*1024*128, b_ff1 + lay*DFF_, nullptr, nullptr, ffh);
        k_ff2_mfma<<<dim3(32, 8), 256, 0, stream>>>(
            ffh, wff2t + (size_t)lay*98304, ffpart);
        k_ff2ln_red<<<BL_, 128, 0, stream>>>(ffpart, b_ff2, ln2_s, ln2_b, src, lay);
    }

    k_vis_gemm<<<dim3(8, VKS), 256, 0, stream>>>(src, w0, vparts);
    k_vis_red<<<32, 256, 0, stream>>>(vparts, visp);

    dim3 mg(T_/64, DFF_/128);   // (32, 8)
    mfma_gemm<true,  LM_ ><<<mg, 256, 0, stream>>>(grdb, w0t, b0, visp, tbi, hab);
    mfma_gemm<false, DFF_><<<mg, 256, 0, stream>>>(hab,  w1t, b1, nullptr, nullptr, hbb);
    mfma_gemm<false, DFF_><<<mg, 256, 0, stream>>>(hbb,  w2t, b2, nullptr, nullptr, hab);
    mfma_gemm<false, DFF_><<<mg, 256, 0, stream>>>(hab,  w3t, b3, nullptr, nullptr, hbb);

    k_final<<<T_, 64, 0, stream>>>(hbb, w4, b4, (float*)d_out);
}